// Round 3
// baseline (940.604 us; speedup 1.0000x reference)
//
#include <hip/hip_runtime.h>
#include <hip/hip_bf16.h>
#include <math.h>

#define B_ 2
#define S_ 2048
#define D_ 2048
#define H_ 16
#define DK_ 128
#define DL_ 512
#define DR_ 64
#define BS_ (B_ * S_)   // 4096

typedef __attribute__((ext_vector_type(8))) short short8;
typedef __attribute__((ext_vector_type(4))) float f32x4;

static __device__ __forceinline__ ushort f2b(float f) {
    union { __hip_bfloat16 h; ushort u; } cvt;
    cvt.h = __float2bfloat16(f);
    return cvt.u;
}

#define GLOAD_LDS16(g, l)                                                         \
    __builtin_amdgcn_global_load_lds(                                             \
        (const __attribute__((address_space(1))) void*)(g),                       \
        (__attribute__((address_space(3))) void*)(l), 16, 0, 0)

// ---------------------------------------------------------------------------
// fp32 -> bf16 elementwise convert (n divisible by 4)
// ---------------------------------------------------------------------------
__global__ __launch_bounds__(256) void cvt_f32_bf16(const float* __restrict__ in,
                                                    ushort* __restrict__ out, int n) {
    int i = (blockIdx.x * 256 + threadIdx.x) * 4;
    if (i >= n) return;
    float4 v = *(const float4*)(in + i);
    ushort4 o;
    o.x = f2b(v.x); o.y = f2b(v.y); o.z = f2b(v.z); o.w = f2b(v.w);
    *(ushort4*)(out + i) = o;
}

// ---------------------------------------------------------------------------
// fp32 (R x C) -> bf16 transposed (C x R).  grid (C/32, R/32), block (32, 8)
// ---------------------------------------------------------------------------
__global__ __launch_bounds__(256) void transpose_cvt(const float* __restrict__ in,
                                                     ushort* __restrict__ out,
                                                     int R, int C) {
    __shared__ float tile[32][33];
    int c0 = blockIdx.x * 32, r0 = blockIdx.y * 32;
    int tx = threadIdx.x, ty = threadIdx.y;
#pragma unroll
    for (int i = 0; i < 4; ++i)
        tile[ty + i * 8][tx] = in[(size_t)(r0 + ty + i * 8) * C + c0 + tx];
    __syncthreads();
#pragma unroll
    for (int i = 0; i < 4; ++i)
        out[(size_t)(c0 + ty + i * 8) * R + r0 + tx] = f2b(tile[tx][ty + i * 8]);
}

// ---------------------------------------------------------------------------
// bf16 [s][d] per (b,h) -> bf16 [b*h][d][s].  grid (128/32, 2048/32, 32), block (32,8)
// ---------------------------------------------------------------------------
__global__ __launch_bounds__(256) void v_transpose(const ushort* __restrict__ vb,
                                                   ushort* __restrict__ vt) {
    __shared__ ushort tile[32][34];
    const int bh = blockIdx.z, b = bh >> 4, h = bh & 15;
    const int d0 = blockIdx.x * 32, s0 = blockIdx.y * 32;
    const int tx = threadIdx.x, ty = threadIdx.y;
    const ushort* src = vb + (size_t)(b * 2048 + s0) * 2048 + h * 128 + d0;
#pragma unroll
    for (int i = 0; i < 4; ++i)
        tile[ty + i * 8][tx] = src[(size_t)(ty + i * 8) * 2048 + tx];  // [s][d]
    __syncthreads();
    ushort* dst = vt + ((size_t)bh * 128 + d0) * 2048 + s0;
#pragma unroll
    for (int i = 0; i < 4; ++i)
        dst[(size_t)(ty + i * 8) * 2048 + tx] = tile[tx][ty + i * 8];  // [d][s]
}

// ---------------------------------------------------------------------------
// RoPE cos/sin tables, matches jnp: freq = (1e-4)^linspace(0,1,16) ++ zeros(16)
// ---------------------------------------------------------------------------
__global__ __launch_bounds__(256) void rope_tables(float* __restrict__ cosT,
                                                   float* __restrict__ sinT) {
    int idx = blockIdx.x * 256 + threadIdx.x;
    int s = idx >> 5, j = idx & 31;
    float c = 1.f, sn = 0.f;
    if (j < 16) {
        float t = (float)j * (1.0f / 15.0f);
        float f = powf(10000.0f, -t);
        float th = (float)s * f;
        c = cosf(th);
        sn = sinf(th);
    }
    cosT[idx] = c;
    sinT[idx] = sn;
}

// ---------------------------------------------------------------------------
// bf16 GEMM, A (MxK) row-major, BT (NxK) row-major, C = A*B (MxN).
// 128x128 tile, BK=32, 4 waves in 2x2, each wave 64x64 via 4x4 16x16 frags.
// ---------------------------------------------------------------------------
template <int OUT_BF16>
__global__ __launch_bounds__(256) void gemm_bt(const ushort* __restrict__ A,
                                               const ushort* __restrict__ BT,
                                               void* __restrict__ Cv,
                                               int M, int N, int K) {
    __shared__ __align__(16) ushort As[128 * 32];
    __shared__ __align__(16) ushort Bs[128 * 32];
    const int tid = threadIdx.x;
    const int lane = tid & 63, wave = tid >> 6;
    const int wr = wave >> 1, wc = wave & 1;
    const int row0 = blockIdx.y * 128, col0 = blockIdx.x * 128;
    const int fr = lane & 15, kg = (lane >> 4) * 8;

    f32x4 acc[4][4] = {};

    const int sr = tid >> 2;
    const int sc8 = (tid & 3) * 8;
    const ushort* ga = A + (size_t)(row0 + sr) * K + sc8;
    const ushort* gb = BT + (size_t)(col0 + sr) * K + sc8;
    ushort* asDst = As + (size_t)(wave * 64) * 8;
    ushort* bsDst = Bs + (size_t)(wave * 64) * 8;

    for (int k0 = 0; k0 < K; k0 += 32) {
        GLOAD_LDS16(ga + k0, asDst);
        GLOAD_LDS16(ga + (size_t)64 * K + k0, asDst + 256 * 8);
        GLOAD_LDS16(gb + k0, bsDst);
        GLOAD_LDS16(gb + (size_t)64 * K + k0, bsDst + 256 * 8);
        __syncthreads();

        short8 af[4], bfr[4];
#pragma unroll
        for (int m = 0; m < 4; ++m)
            af[m] = *(const short8*)&As[(wr * 64 + m * 16 + fr) * 32 + kg];
#pragma unroll
        for (int n = 0; n < 4; ++n)
            bfr[n] = *(const short8*)&Bs[(wc * 64 + n * 16 + fr) * 32 + kg];
#pragma unroll
        for (int m = 0; m < 4; ++m)
#pragma unroll
            for (int n = 0; n < 4; ++n)
                acc[m][n] = __builtin_amdgcn_mfma_f32_16x16x32_bf16(af[m], bfr[n],
                                                                    acc[m][n], 0, 0, 0);
        __syncthreads();
    }

    const int rbase = row0 + wr * 64 + (lane >> 4) * 4;
    const int cbase = col0 + wc * 64 + fr;
    if constexpr (OUT_BF16) {
        ushort* C = (ushort*)Cv;
#pragma unroll
        for (int m = 0; m < 4; ++m)
#pragma unroll
            for (int n = 0; n < 4; ++n)
#pragma unroll
                for (int j = 0; j < 4; ++j)
                    C[(size_t)(rbase + m * 16 + j) * N + cbase + n * 16] = f2b(acc[m][n][j]);
    } else {
        float* C = (float*)Cv;
#pragma unroll
        for (int m = 0; m < 4; ++m)
#pragma unroll
            for (int n = 0; n < 4; ++n)
#pragma unroll
                for (int j = 0; j < 4; ++j)
                    C[(size_t)(rbase + m * 16 + j) * N + cbase + n * 16] = acc[m][n][j];
    }
}

// ---------------------------------------------------------------------------
// q: rmsnorm then RoPE on first 64 dims; output pre-scaled by 1/sqrt(128).
// ---------------------------------------------------------------------------
__global__ __launch_bounds__(256) void q_norm_rope(const float* __restrict__ qp,
                                                   const float* __restrict__ w,
                                                   const float* __restrict__ cosT,
                                                   const float* __restrict__ sinT,
                                                   ushort* __restrict__ qb) {
    const int lane = threadIdx.x & 63, wave = threadIdx.x >> 6;
    const int rowId = blockIdx.x * 4 + wave;
    const int bs = rowId >> 4, h = rowId & 15;
    const int s = bs & (S_ - 1);
    const float scale = 0.08838834764831845f;  // 1/sqrt(128) folded into q
    const float* src = qp + (size_t)bs * 2048 + h * 128;
    float e0 = src[lane], e1 = src[64 + lane];
    float ss = e0 * e0 + e1 * e1;
#pragma unroll
    for (int m = 1; m < 64; m <<= 1) ss += __shfl_xor(ss, m, 64);
    float r = rsqrtf(ss * (1.0f / 128.0f) + 1e-6f);
    float xn0 = e0 * r * w[lane];
    float xn1 = e1 * r * w[64 + lane];
    int j = lane & 31;
    float c = cosT[s * 32 + j], sn = sinT[s * 32 + j];
    float p = __shfl_xor(xn0, 32, 64);
    float y0 = (lane < 32) ? (xn0 * c + p * sn) : (-p * sn + xn0 * c);
    ushort* dst = qb + (size_t)bs * 2048 + h * 128;
    dst[lane] = f2b(y0 * scale);
    dst[64 + lane] = f2b(xn1 * scale);
}

// ---------------------------------------------------------------------------
// k: RoPE(k_rope) ++ k_nope, then rmsnorm over 128. 1 wave = 1 row.
// ---------------------------------------------------------------------------
__global__ __launch_bounds__(256) void k_assemble(const float* __restrict__ krp,
                                                  const float* __restrict__ knp,
                                                  const float* __restrict__ w,
                                                  const float* __restrict__ cosT,
                                                  const float* __restrict__ sinT,
                                                  ushort* __restrict__ kb) {
    const int lane = threadIdx.x & 63, wave = threadIdx.x >> 6;
    const int rowId = blockIdx.x * 4 + wave;
    const int bs = rowId >> 4, h = rowId & 15;
    const int s = bs & (S_ - 1);
    float e0 = krp[(size_t)bs * 1024 + h * 64 + lane];
    float e1 = knp[(size_t)bs * 1024 + h * 64 + lane];
    int j = lane & 31;
    float c = cosT[s * 32 + j], sn = sinT[s * 32 + j];
    float p = __shfl_xor(e0, 32, 64);
    float y0 = (lane < 32) ? (e0 * c + p * sn) : (-p * sn + e0 * c);
    float ss = y0 * y0 + e1 * e1;
#pragma unroll
    for (int m = 1; m < 64; m <<= 1) ss += __shfl_xor(ss, m, 64);
    float r = rsqrtf(ss * (1.0f / 128.0f) + 1e-6f);
    ushort* dst = kb + (size_t)bs * 2048 + h * 128;
    dst[lane] = f2b(y0 * r * w[lane]);
    dst[64 + lane] = f2b(e1 * r * w[64 + lane]);
}

// ---------------------------------------------------------------------------
// causal flash attention, zero-barrier. grid (S/64, B*H), block 256.
// 4 waves x 16 q rows; KV tile = 64. Q,K [bs][h*128]; V pre-transposed
// [bh][128][2048]. P via per-wave LDS (stride 80, granule-XOR swizzle).
// q_b is pre-scaled by 1/sqrt(DK), so scores need no scaling here.
// ---------------------------------------------------------------------------
__global__ __launch_bounds__(256) void attn_fwd(const ushort* __restrict__ Q,
                                                const ushort* __restrict__ Kb,
                                                const ushort* __restrict__ Vt,
                                                ushort* __restrict__ Ob) {
    __shared__ __align__(16) ushort Pl[4][16 * 80];  // per-wave, stride 80
    const int tid = threadIdx.x, lane = tid & 63, wave = tid >> 6;
    const int bh = blockIdx.y, b = bh >> 4;
    const int q0 = ((int)gridDim.x - 1 - (int)blockIdx.x) * 64;  // heaviest first
    const int fr = lane & 15, g = lane >> 4, kg = g * 8;

    const ushort* qbase = Q + (size_t)(b * S_) * 2048 + (bh & 15) * 128;
    const ushort* kbase = Kb + (size_t)(b * S_) * 2048 + (bh & 15) * 128;
    const ushort* vtbase = Vt + (size_t)bh * 128 * 2048;
    ushort* myP = Pl[wave];

    // Q fragments: row = q0 + wave*16 + fr
    short8 qf[4];
    const ushort* qrow = qbase + (size_t)(q0 + wave * 16 + fr) * 2048;
#pragma unroll
    for (int kb = 0; kb < 4; ++kb) qf[kb] = *(const short8*)(qrow + kb * 32 + kg);

    f32x4 Oacc[8] = {};
    float mrow[4], lrow[4];
#pragma unroll
    for (int j = 0; j < 4; ++j) { mrow[j] = -1e30f; lrow[j] = 0.f; }
    const int ntiles = q0 / 64 + 1;

    for (int t = 0; t < ntiles; ++t) {
        const int kt0 = t * 64;
        // ---- QK^T: 4 col-frags x 4 k-slabs, K direct from global (L2-hot)
        f32x4 sc[4] = {};
#pragma unroll
        for (int n = 0; n < 4; ++n) {
            const ushort* krow = kbase + (size_t)(kt0 + n * 16 + fr) * 2048;
#pragma unroll
            for (int kb = 0; kb < 4; ++kb) {
                short8 kf = *(const short8*)(krow + kb * 32 + kg);
                sc[n] = __builtin_amdgcn_mfma_f32_16x16x32_bf16(qf[kb], kf, sc[n], 0, 0, 0);
            }
        }
        // ---- causal mask: only the diagonal tile needs it
        if (t == ntiles - 1) {
#pragma unroll
            for (int n = 0; n < 4; ++n) {
                int kpos = kt0 + n * 16 + fr;
#pragma unroll
                for (int j = 0; j < 4; ++j) {
                    int qr = q0 + wave * 16 + g * 4 + j;
                    if (kpos > qr) sc[n][j] = -1e30f;
                }
            }
        }
        // ---- online softmax
        float tmax[4];
#pragma unroll
        for (int j = 0; j < 4; ++j)
            tmax[j] = fmaxf(fmaxf(sc[0][j], sc[1][j]), fmaxf(sc[2][j], sc[3][j]));
#pragma unroll
        for (int m = 1; m < 16; m <<= 1)
#pragma unroll
            for (int j = 0; j < 4; ++j) tmax[j] = fmaxf(tmax[j], __shfl_xor(tmax[j], m, 64));
        float alpha[4], rsum[4];
#pragma unroll
        for (int j = 0; j < 4; ++j) {
            float mn = fmaxf(mrow[j], tmax[j]);
            alpha[j] = __expf(mrow[j] - mn);
            mrow[j] = mn;
            rsum[j] = 0.f;
        }
#pragma unroll
        for (int n = 0; n < 4; ++n)
#pragma unroll
            for (int j = 0; j < 4; ++j) {
                float pv = __expf(sc[n][j] - mrow[j]);
                sc[n][j] = pv;
                rsum[j] += pv;
            }
#pragma unroll
        for (int m = 1; m < 16; m <<= 1)
#pragma unroll
            for (int j = 0; j < 4; ++j) rsum[j] += __shfl_xor(rsum[j], m, 64);
#pragma unroll
        for (int j = 0; j < 4; ++j) lrow[j] = lrow[j] * alpha[j] + rsum[j];
#pragma unroll
        for (int n8 = 0; n8 < 8; ++n8)
#pragma unroll
            for (int j = 0; j < 4; ++j) Oacc[n8][j] *= alpha[j];
        // ---- P -> per-wave LDS, row q (stride 80), 16B-granule XOR swizzle by q>>2
#pragma unroll
        for (int n = 0; n < 4; ++n)
#pragma unroll
            for (int j = 0; j < 4; ++j) {
                int q = g * 4 + j;
                int c = n * 16 + fr;
                int cs = ((((c >> 3) ^ (q >> 2)) & 7) << 3) | (c & 7);
                myP[q * 80 + cs] = f2b(sc[n][j]);
            }
        // ---- PV: A = P row fr (unswizzle), B = V^T rows direct from global
        short8 pa[2];
#pragma unroll
        for (int ks = 0; ks < 2; ++ks)
            pa[ks] = *(const short8*)&myP[fr * 80 + ((((ks * 4 + g) ^ (fr >> 2)) & 7) << 3)];
#pragma unroll
        for (int n8 = 0; n8 < 8; ++n8) {
            const ushort* vrow = vtbase + (size_t)(n8 * 16 + fr) * 2048 + kt0;
#pragma unroll
            for (int ks = 0; ks < 2; ++ks) {
                short8 vf = *(const short8*)(vrow + ks * 32 + kg);
                Oacc[n8] = __builtin_amdgcn_mfma_f32_16x16x32_bf16(pa[ks], vf, Oacc[n8], 0, 0, 0);
            }
        }
    }
    // ---- epilogue
#pragma unroll
    for (int j = 0; j < 4; ++j) {
        int qr = q0 + wave * 16 + g * 4 + j;
        float inv = 1.0f / lrow[j];
        ushort* orow = Ob + (size_t)(b * S_ + qr) * 2048 + (bh & 15) * 128;
#pragma unroll
        for (int n8 = 0; n8 < 8; ++n8) orow[n8 * 16 + fr] = f2b(Oacc[n8][j] * inv);
    }
}

// ---------------------------------------------------------------------------
extern "C" void kernel_launch(void* const* d_in, const int* in_sizes, int n_in,
                              void* d_out, int out_size, void* d_ws, size_t ws_size,
                              hipStream_t stream) {
    (void)in_sizes; (void)n_in; (void)out_size; (void)ws_size;
    const float* x = (const float*)d_in[0];
    const float* wq = (const float*)d_in[1];
    const float* w_kv_down = (const float*)d_in[2];
    const float* w_k_rope = (const float*)d_in[3];
    const float* w_k_nope = (const float*)d_in[4];
    const float* wv = (const float*)d_in[5];
    const float* wo = (const float*)d_in[6];
    const float* q_norm_w = (const float*)d_in[7];
    const float* k_norm_w = (const float*)d_in[8];
    float* out = (float*)d_out;

    char* ws = (char*)d_ws;
    size_t off = 0;
    auto alloc = [&](size_t bytes) {
        off = (off + 255) & ~(size_t)255;
        void* p = ws + off;
        off += bytes;
        return p;
    };
    ushort* xb = (ushort*)alloc((size_t)BS_ * 2048 * 2);
    ushort* wq_t = (ushort*)alloc((size_t)2048 * 2048 * 2);
    ushort* wkv_t = (ushort*)alloc((size_t)512 * 2048 * 2);
    ushort* wkr_t = (ushort*)alloc((size_t)1024 * 512 * 2);
    ushort* wkn_t = (ushort*)alloc((size_t)1024 * 512 * 2);
    ushort* wv_t = (ushort*)alloc((size_t)2048 * 512 * 2);
    ushort* wo_t = (ushort*)alloc((size_t)2048 * 2048 * 2);
    float* q_pre = (float*)alloc((size_t)BS_ * 2048 * 4);
    ushort* latent_b = (ushort*)alloc((size_t)BS_ * 512 * 2);
    float* kr_pre = (float*)alloc((size_t)BS_ * 1024 * 4);
    float* kn_pre = (float*)alloc((size_t)BS_ * 1024 * 4);
    ushort* v_b = (ushort*)alloc((size_t)BS_ * 2048 * 2);
    ushort* q_b = (ushort*)alloc((size_t)BS_ * 2048 * 2);
    ushort* k_b = (ushort*)alloc((size_t)BS_ * 2048 * 2);
    ushort* ao_b = (ushort*)alloc((size_t)BS_ * 2048 * 2);
    float* cosT = (float*)alloc((size_t)S_ * 32 * 4);
    float* sinT = (float*)alloc((size_t)S_ * 32 * 4);
    // vt aliases q_pre (32MB >= 16MB needed); q_pre is dead after q_norm_rope.
    ushort* vt = (ushort*)q_pre;

    // prep
    cvt_f32_bf16<<<(BS_ * 2048 / 4 + 255) / 256, 256, 0, stream>>>(x, xb, BS_ * 2048);
    transpose_cvt<<<dim3(2048 / 32, 2048 / 32), dim3(32, 8), 0, stream>>>(wq, wq_t, 2048, 2048);
    transpose_cvt<<<dim3(512 / 32, 2048 / 32), dim3(32, 8), 0, stream>>>(w_kv_down, wkv_t, 2048, 512);
    transpose_cvt<<<dim3(1024 / 32, 512 / 32), dim3(32, 8), 0, stream>>>(w_k_rope, wkr_t, 512, 1024);
    transpose_cvt<<<dim3(1024 / 32, 512 / 32), dim3(32, 8), 0, stream>>>(w_k_nope, wkn_t, 512, 1024);
    transpose_cvt<<<dim3(2048 / 32, 512 / 32), dim3(32, 8), 0, stream>>>(wv, wv_t, 512, 2048);
    transpose_cvt<<<dim3(2048 / 32, 2048 / 32), dim3(32, 8), 0, stream>>>(wo, wo_t, 2048, 2048);
    rope_tables<<<S_ * 32 / 256, 256, 0, stream>>>(cosT, sinT);

    // projections
    gemm_bt<0><<<dim3(2048 / 128, BS_ / 128), 256, 0, stream>>>(xb, wq_t, q_pre, BS_, 2048, 2048);
    gemm_bt<1><<<dim3(512 / 128, BS_ / 128), 256, 0, stream>>>(xb, wkv_t, latent_b, BS_, 512, 2048);
    gemm_bt<0><<<dim3(1024 / 128, BS_ / 128), 256, 0, stream>>>(latent_b, wkr_t, kr_pre, BS_, 1024, 512);
    gemm_bt<0><<<dim3(1024 / 128, BS_ / 128), 256, 0, stream>>>(latent_b, wkn_t, kn_pre, BS_, 1024, 512);
    gemm_bt<1><<<dim3(2048 / 128, BS_ / 128), 256, 0, stream>>>(latent_b, wv_t, v_b, BS_, 2048, 512);

    // norms + rope (q_pre consumed here)
    q_norm_rope<<<BS_ * H_ / 4, 256, 0, stream>>>(q_pre, q_norm_w, cosT, sinT, q_b);
    k_assemble<<<BS_ * H_ / 4, 256, 0, stream>>>(kr_pre, kn_pre, k_norm_w, cosT, sinT, k_b);

    // V -> [bh][d][s] (writes over dead q_pre)
    v_transpose<<<dim3(128 / 32, 2048 / 32, B_ * H_), dim3(32, 8), 0, stream>>>(v_b, vt);

    // attention
    attn_fwd<<<dim3(S_ / 64, B_ * H_), 256, 0, stream>>>(q_b, k_b, vt, ao_b);

    // output projection
    gemm_bt<0><<<dim3(2048 / 128, BS_ / 128), 256, 0, stream>>>(ao_b, wo_t, out, BS_, 2048, 2048);
}

// Round 6
// 480.140 us; speedup vs baseline: 1.9590x; 1.9590x over previous
//
#include <hip/hip_runtime.h>
#include <hip/hip_bf16.h>
#include <math.h>

#define B_ 2
#define S_ 2048
#define D_ 2048
#define H_ 16
#define DK_ 128
#define DL_ 512
#define DR_ 64
#define BS_ (B_ * S_)   // 4096

typedef __attribute__((ext_vector_type(8))) short short8;
typedef __attribute__((ext_vector_type(4))) float f32x4;

static __device__ __forceinline__ ushort f2b(float f) {
    union { __hip_bfloat16 h; ushort u; } cvt;
    cvt.h = __float2bfloat16(f);
    return cvt.u;
}

#define GLOAD_LDS16(g, l)                                                         \
    __builtin_amdgcn_global_load_lds(                                             \
        (const __attribute__((address_space(1))) void*)(g),                       \
        (__attribute__((address_space(3))) void*)(l), 16, 0, 0)

// ---------------------------------------------------------------------------
// fp32 -> bf16 elementwise convert (n divisible by 4)
// ---------------------------------------------------------------------------
__global__ __launch_bounds__(256) void cvt_f32_bf16(const float* __restrict__ in,
                                                    ushort* __restrict__ out, int n) {
    int i = (blockIdx.x * 256 + threadIdx.x) * 4;
    if (i >= n) return;
    float4 v = *(const float4*)(in + i);
    ushort4 o;
    o.x = f2b(v.x); o.y = f2b(v.y); o.z = f2b(v.z); o.w = f2b(v.w);
    *(ushort4*)(out + i) = o;
}

// ---------------------------------------------------------------------------
// fp32 (R x C) -> bf16 transposed (C x R).  grid (C/32, R/32), block (32, 8)
// ---------------------------------------------------------------------------
__global__ __launch_bounds__(256) void transpose_cvt(const float* __restrict__ in,
                                                     ushort* __restrict__ out,
                                                     int R, int C) {
    __shared__ float tile[32][33];
    int c0 = blockIdx.x * 32, r0 = blockIdx.y * 32;
    int tx = threadIdx.x, ty = threadIdx.y;
#pragma unroll
    for (int i = 0; i < 4; ++i)
        tile[ty + i * 8][tx] = in[(size_t)(r0 + ty + i * 8) * C + c0 + tx];
    __syncthreads();
#pragma unroll
    for (int i = 0; i < 4; ++i)
        out[(size_t)(c0 + ty + i * 8) * R + r0 + tx] = f2b(tile[tx][ty + i * 8]);
}

// ---------------------------------------------------------------------------
// bf16 [s][d] per (b,h) -> bf16 [b*h][d][s].  grid (128/32, 2048/32, 32), block (32,8)
// ---------------------------------------------------------------------------
__global__ __launch_bounds__(256) void v_transpose(const ushort* __restrict__ vb,
                                                   ushort* __restrict__ vt) {
    __shared__ ushort tile[32][34];
    const int bh = blockIdx.z, b = bh >> 4, h = bh & 15;
    const int d0 = blockIdx.x * 32, s0 = blockIdx.y * 32;
    const int tx = threadIdx.x, ty = threadIdx.y;
    const ushort* src = vb + (size_t)(b * 2048 + s0) * 2048 + h * 128 + d0;
#pragma unroll
    for (int i = 0; i < 4; ++i)
        tile[ty + i * 8][tx] = src[(size_t)(ty + i * 8) * 2048 + tx];  // [s][d]
    __syncthreads();
    ushort* dst = vt + ((size_t)bh * 128 + d0) * 2048 + s0;
#pragma unroll
    for (int i = 0; i < 4; ++i)
        dst[(size_t)(ty + i * 8) * 2048 + tx] = tile[tx][ty + i * 8];  // [d][s]
}

// ---------------------------------------------------------------------------
// RoPE cos/sin tables, matches jnp: freq = (1e-4)^linspace(0,1,16) ++ zeros(16)
// ---------------------------------------------------------------------------
__global__ __launch_bounds__(256) void rope_tables(float* __restrict__ cosT,
                                                   float* __restrict__ sinT) {
    int idx = blockIdx.x * 256 + threadIdx.x;
    int s = idx >> 5, j = idx & 31;
    float c = 1.f, sn = 0.f;
    if (j < 16) {
        float t = (float)j * (1.0f / 15.0f);
        float f = powf(10000.0f, -t);
        float th = (float)s * f;
        c = cosf(th);
        sn = sinf(th);
    }
    cosT[idx] = c;
    sinT[idx] = sn;
}

// ---------------------------------------------------------------------------
// bf16 GEMM, A (MxK) row-major, BT (NxK) row-major, C = A*B (MxN).
// 128x128 tile, BK=32, 4 waves in 2x2, each wave 64x64 via 4x4 16x16 frags.
// ---------------------------------------------------------------------------
template <int OUT_BF16>
__global__ __launch_bounds__(256) void gemm_bt(const ushort* __restrict__ A,
                                               const ushort* __restrict__ BT,
                                               void* __restrict__ Cv,
                                               int M, int N, int K) {
    __shared__ __align__(16) ushort As[128 * 32];
    __shared__ __align__(16) ushort Bs[128 * 32];
    const int tid = threadIdx.x;
    const int lane = tid & 63, wave = tid >> 6;
    const int wr = wave >> 1, wc = wave & 1;
    const int row0 = blockIdx.y * 128, col0 = blockIdx.x * 128;
    const int fr = lane & 15, kg = (lane >> 4) * 8;

    f32x4 acc[4][4] = {};

    const int sr = tid >> 2;
    const int sc8 = (tid & 3) * 8;
    const ushort* ga = A + (size_t)(row0 + sr) * K + sc8;
    const ushort* gb = BT + (size_t)(col0 + sr) * K + sc8;
    ushort* asDst = As + (size_t)(wave * 64) * 8;
    ushort* bsDst = Bs + (size_t)(wave * 64) * 8;

    for (int k0 = 0; k0 < K; k0 += 32) {
        GLOAD_LDS16(ga + k0, asDst);
        GLOAD_LDS16(ga + (size_t)64 * K + k0, asDst + 256 * 8);
        GLOAD_LDS16(gb + k0, bsDst);
        GLOAD_LDS16(gb + (size_t)64 * K + k0, bsDst + 256 * 8);
        __syncthreads();

        short8 af[4], bfr[4];
#pragma unroll
        for (int m = 0; m < 4; ++m)
            af[m] = *(const short8*)&As[(wr * 64 + m * 16 + fr) * 32 + kg];
#pragma unroll
        for (int n = 0; n < 4; ++n)
            bfr[n] = *(const short8*)&Bs[(wc * 64 + n * 16 + fr) * 32 + kg];
#pragma unroll
        for (int m = 0; m < 4; ++m)
#pragma unroll
            for (int n = 0; n < 4; ++n)
                acc[m][n] = __builtin_amdgcn_mfma_f32_16x16x32_bf16(af[m], bfr[n],
                                                                    acc[m][n], 0, 0, 0);
        __syncthreads();
    }

    const int rbase = row0 + wr * 64 + (lane >> 4) * 4;
    const int cbase = col0 + wc * 64 + fr;
    if constexpr (OUT_BF16) {
        ushort* C = (ushort*)Cv;
#pragma unroll
        for (int m = 0; m < 4; ++m)
#pragma unroll
            for (int n = 0; n < 4; ++n)
#pragma unroll
                for (int j = 0; j < 4; ++j)
                    C[(size_t)(rbase + m * 16 + j) * N + cbase + n * 16] = f2b(acc[m][n][j]);
    } else {
        float* C = (float*)Cv;
#pragma unroll
        for (int m = 0; m < 4; ++m)
#pragma unroll
            for (int n = 0; n < 4; ++n)
#pragma unroll
                for (int j = 0; j < 4; ++j)
                    C[(size_t)(rbase + m * 16 + j) * N + cbase + n * 16] = acc[m][n][j];
    }
}

// ---------------------------------------------------------------------------
// q: rmsnorm then RoPE on first 64 dims; output pre-scaled by 1/sqrt(128).
// ---------------------------------------------------------------------------
__global__ __launch_bounds__(256) void q_norm_rope(const float* __restrict__ qp,
                                                   const float* __restrict__ w,
                                                   const float* __restrict__ cosT,
                                                   const float* __restrict__ sinT,
                                                   ushort* __restrict__ qb) {
    const int lane = threadIdx.x & 63, wave = threadIdx.x >> 6;
    const int rowId = blockIdx.x * 4 + wave;
    const int bs = rowId >> 4, h = rowId & 15;
    const int s = bs & (S_ - 1);
    const float scale = 0.08838834764831845f;  // 1/sqrt(128) folded into q
    const float* src = qp + (size_t)bs * 2048 + h * 128;
    float e0 = src[lane], e1 = src[64 + lane];
    float ss = e0 * e0 + e1 * e1;
#pragma unroll
    for (int m = 1; m < 64; m <<= 1) ss += __shfl_xor(ss, m, 64);
    float r = rsqrtf(ss * (1.0f / 128.0f) + 1e-6f);
    float xn0 = e0 * r * w[lane];
    float xn1 = e1 * r * w[64 + lane];
    int j = lane & 31;
    float c = cosT[s * 32 + j], sn = sinT[s * 32 + j];
    float p = __shfl_xor(xn0, 32, 64);
    float y0 = (lane < 32) ? (xn0 * c + p * sn) : (-p * sn + xn0 * c);
    ushort* dst = qb + (size_t)bs * 2048 + h * 128;
    dst[lane] = f2b(y0 * scale);
    dst[64 + lane] = f2b(xn1 * scale);
}

// ---------------------------------------------------------------------------
// k: RoPE(k_rope) ++ k_nope, then rmsnorm over 128. 1 wave = 1 row.
// ---------------------------------------------------------------------------
__global__ __launch_bounds__(256) void k_assemble(const float* __restrict__ krp,
                                                  const float* __restrict__ knp,
                                                  const float* __restrict__ w,
                                                  const float* __restrict__ cosT,
                                                  const float* __restrict__ sinT,
                                                  ushort* __restrict__ kb) {
    const int lane = threadIdx.x & 63, wave = threadIdx.x >> 6;
    const int rowId = blockIdx.x * 4 + wave;
    const int bs = rowId >> 4, h = rowId & 15;
    const int s = bs & (S_ - 1);
    float e0 = krp[(size_t)bs * 1024 + h * 64 + lane];
    float e1 = knp[(size_t)bs * 1024 + h * 64 + lane];
    int j = lane & 31;
    float c = cosT[s * 32 + j], sn = sinT[s * 32 + j];
    float p = __shfl_xor(e0, 32, 64);
    float y0 = (lane < 32) ? (e0 * c + p * sn) : (-p * sn + e0 * c);
    float ss = y0 * y0 + e1 * e1;
#pragma unroll
    for (int m = 1; m < 64; m <<= 1) ss += __shfl_xor(ss, m, 64);
    float r = rsqrtf(ss * (1.0f / 128.0f) + 1e-6f);
    ushort* dst = kb + (size_t)bs * 2048 + h * 128;
    dst[lane] = f2b(y0 * r * w[lane]);
    dst[64 + lane] = f2b(e1 * r * w[64 + lane]);
}

// ---------------------------------------------------------------------------
// causal flash attention. grid (8, B*H), block 512 (8 waves x 16 q rows).
// Each block processes q-tiles {15-bx, bx} (128 rows each) -> exactly 36
// KV-tile iterations per block (perfect balance). KV tile = 64, K and V^T
// staged in LDS (double-buffered, global_load_lds w16, subtiled layout ->
// conflict-free ds_read_b128), prefetched one tile ahead.
// LDS subtile layout: subtile si holds 16 rows x 32 cols as [fr16][g4*8elem],
// i.e. element (fr, c) at si*512 + fr*32 + c. One staging instr = 1KB.
// K subtile si: rows kt0+ (si>>2)*16 + fr, cols (si&3)*32 + sg*8
// V subtile si: d-rows (si>>1)*16 + fr, k-cols kt0 + (si&1)*32 + sg*8
// P: per-wave 16 rows x 64 cols, stride 64, 16B-granule XOR swizzle by row:
//   phys_granule = logical_granule ^ (row & 7)  (bijective per row; read of
//   granule ks*4+g for row fr hits banks 4*((ks*4+g)^(fr&7)) -> min-cycle).
// Total LDS = 32K (K) + 32K (V) + 16K (P) = 80KB -> 2 blocks/CU.
// ---------------------------------------------------------------------------
__global__ __launch_bounds__(512) void attn_fwd(const ushort* __restrict__ Q,
                                                const ushort* __restrict__ Kb,
                                                const ushort* __restrict__ Vt,
                                                ushort* __restrict__ Ob) {
    __shared__ __align__(16) ushort Kls[2][8192];   // 2 x 16KB
    __shared__ __align__(16) ushort Vls[2][8192];   // 2 x 16KB
    __shared__ __align__(16) ushort Pls[8][1024];   // per-wave P, 16 x 64 swizzled
    const int tid = threadIdx.x, lane = tid & 63, wave = tid >> 6;
    const int bh = blockIdx.y, b = bh >> 4, h = bh & 15;
    const int fr = lane & 15, g = lane >> 4;        // MFMA fragment coords
    const int sfr = lane >> 2, sg = lane & 3;       // staging coords

    const ushort* qbase = Q + (size_t)(b * S_) * 2048 + h * 128;
    const ushort* kbase = Kb + (size_t)(b * S_) * 2048 + h * 128;
    const ushort* vtbase = Vt + (size_t)bh * 128 * 2048;
    ushort* myP = Pls[wave];

    auto stage = [&](int kt0, int bufi) {
#pragma unroll
        for (int i = 0; i < 2; ++i) {
            const int si = wave * 2 + i;
            GLOAD_LDS16(kbase + (size_t)(kt0 + (si >> 2) * 16 + sfr) * 2048 +
                            (si & 3) * 32 + sg * 8,
                        &Kls[bufi][si * 512]);
            GLOAD_LDS16(vtbase + (size_t)((si >> 1) * 16 + sfr) * 2048 + kt0 +
                            (si & 1) * 32 + sg * 8,
                        &Vls[bufi][si * 512]);
        }
    };

#pragma unroll 1
    for (int pi = 0; pi < 2; ++pi) {
        const int qi = pi ? (int)blockIdx.x : 15 - (int)blockIdx.x;  // heavy first
        const int q0 = qi * 128;
        const int nt = 2 * qi + 2;

        // Q fragments for this pass: rows q0 + wave*16 + fr
        short8 qf[4];
        const ushort* qrow = qbase + (size_t)(q0 + wave * 16 + fr) * 2048;
#pragma unroll
        for (int kb = 0; kb < 4; ++kb) qf[kb] = *(const short8*)(qrow + kb * 32 + g * 8);

        f32x4 Oacc[8] = {};
        float mrow[4], lrow[4];
#pragma unroll
        for (int j = 0; j < 4; ++j) { mrow[j] = -1e30f; lrow[j] = 0.f; }

        stage(0, 0);
        for (int t = 0; t < nt; ++t) {
            __syncthreads();                     // drains vmcnt: tile t visible
            if (t + 1 < nt) stage((t + 1) * 64, (t + 1) & 1);
            const ushort* Kc = Kls[t & 1];
            const ushort* Vc = Vls[t & 1];
            const int kt0 = t * 64;
            // ---- QK^T
            f32x4 sc[4] = {};
#pragma unroll
            for (int n = 0; n < 4; ++n)
#pragma unroll
                for (int kb = 0; kb < 4; ++kb) {
                    short8 kf = *(const short8*)&Kc[(n * 4 + kb) * 512 + fr * 32 + g * 8];
                    sc[n] = __builtin_amdgcn_mfma_f32_16x16x32_bf16(qf[kb], kf, sc[n], 0, 0, 0);
                }
            // ---- causal mask (only last 2 tiles can touch the diagonal)
            if (t >= nt - 2) {
#pragma unroll
                for (int n = 0; n < 4; ++n) {
                    int kpos = kt0 + n * 16 + fr;
#pragma unroll
                    for (int j = 0; j < 4; ++j) {
                        int qr = q0 + wave * 16 + g * 4 + j;
                        if (kpos > qr) sc[n][j] = -1e30f;
                    }
                }
            }
            // ---- online softmax (reduce over fr: 4 rounds of 16-wide xor)
            float tmax[4];
#pragma unroll
            for (int j = 0; j < 4; ++j)
                tmax[j] = fmaxf(fmaxf(sc[0][j], sc[1][j]), fmaxf(sc[2][j], sc[3][j]));
#pragma unroll
            for (int m = 1; m < 16; m <<= 1)
#pragma unroll
                for (int j = 0; j < 4; ++j) tmax[j] = fmaxf(tmax[j], __shfl_xor(tmax[j], m, 64));
            float alpha[4], rsum[4];
#pragma unroll
            for (int j = 0; j < 4; ++j) {
                float mn = fmaxf(mrow[j], tmax[j]);
                alpha[j] = __expf(mrow[j] - mn);
                mrow[j] = mn;
                rsum[j] = 0.f;
            }
#pragma unroll
            for (int n = 0; n < 4; ++n)
#pragma unroll
                for (int j = 0; j < 4; ++j) {
                    float pv = __expf(sc[n][j] - mrow[j]);
                    sc[n][j] = pv;
                    rsum[j] += pv;
                }
#pragma unroll
            for (int m = 1; m < 16; m <<= 1)
#pragma unroll
                for (int j = 0; j < 4; ++j) rsum[j] += __shfl_xor(rsum[j], m, 64);
#pragma unroll
            for (int j = 0; j < 4; ++j) lrow[j] = lrow[j] * alpha[j] + rsum[j];
#pragma unroll
            for (int n8 = 0; n8 < 8; ++n8)
#pragma unroll
                for (int j = 0; j < 4; ++j) Oacc[n8][j] *= alpha[j];
            // ---- P -> per-wave LDS, row q = g*4+j, col n*16+fr, granule-XOR swizzle
#pragma unroll
            for (int n = 0; n < 4; ++n)
#pragma unroll
                for (int j = 0; j < 4; ++j) {
                    int q = g * 4 + j;
                    int cg = n * 2 + (fr >> 3);                       // logical granule
                    int cs = (((cg ^ q) & 7) << 3) | (fr & 7);        // swizzled offset
                    myP[q * 64 + cs] = f2b(sc[n][j]);
                }
            // ---- PV (A = P rows, B = V^T subtiles; wave-private P: lgkm only)
            short8 pa[2];
#pragma unroll
            for (int ks = 0; ks < 2; ++ks) {
                int pg = ((ks * 4 + g) ^ fr) & 7;                     // phys granule
                pa[ks] = *(const short8*)&myP[fr * 64 + (pg << 3)];
            }
#pragma unroll
            for (int n8 = 0; n8 < 8; ++n8)
#pragma unroll
                for (int ks = 0; ks < 2; ++ks) {
                    short8 vf = *(const short8*)&Vc[(n8 * 2 + ks) * 512 + fr * 32 + g * 8];
                    Oacc[n8] = __builtin_amdgcn_mfma_f32_16x16x32_bf16(pa[ks], vf, Oacc[n8], 0, 0, 0);
                }
        }
        // ---- epilogue
#pragma unroll
        for (int j = 0; j < 4; ++j) {
            int qr = q0 + wave * 16 + g * 4 + j;
            float inv = 1.0f / lrow[j];
            ushort* orow = Ob + (size_t)(b * S_ + qr) * 2048 + h * 128;
#pragma unroll
            for (int n8 = 0; n8 < 8; ++n8) orow[n8 * 16 + fr] = f2b(Oacc[n8][j] * inv);
        }
        __syncthreads();  // protect LDS buffers before next pass restages
    }
}

// ---------------------------------------------------------------------------
extern "C" void kernel_launch(void* const* d_in, const int* in_sizes, int n_in,
                              void* d_out, int out_size, void* d_ws, size_t ws_size,
                              hipStream_t stream) {
    (void)in_sizes; (void)n_in; (void)out_size; (void)ws_size;
    const float* x = (const float*)d_in[0];
    const float* wq = (const float*)d_in[1];
    const float* w_kv_down = (const float*)d_in[2];
    const float* w_k_rope = (const float*)d_in[3];
    const float* w_k_nope = (const float*)d_in[4];
    const float* wv = (const float*)d_in[5];
    const float* wo = (const float*)d_in[6];
    const float* q_norm_w = (const float*)d_in[7];
    const float* k_norm_w = (const float*)d_in[8];
    float* out = (float*)d_out;

    char* ws = (char*)d_ws;
    size_t off = 0;
    auto alloc = [&](size_t bytes) {
        off = (off + 255) & ~(size_t)255;
        void* p = ws + off;
        off += bytes;
        return p;
    };
    ushort* xb = (ushort*)alloc((size_t)BS_ * 2048 * 2);
    ushort* wq_t = (ushort*)alloc((size_t)2048 * 2048 * 2);
    ushort* wkv_t = (ushort*)alloc((size_t)512 * 2048 * 2);
    ushort* wkr_t = (ushort*)alloc((size_t)1024 * 512 * 2);
    ushort* wkn_t = (ushort*)alloc((size_t)1024 * 512 * 2);
    ushort* wv_t = (ushort*)alloc((size_t)2048 * 512 * 2);
    ushort* wo_t = (ushort*)alloc((size_t)2048 * 2048 * 2);
    float* q_pre = (float*)alloc((size_t)BS_ * 2048 * 4);
    ushort* latent_b = (ushort*)alloc((size_t)BS_ * 512 * 2);
    float* kr_pre = (float*)alloc((size_t)BS_ * 1024 * 4);
    float* kn_pre = (float*)alloc((size_t)BS_ * 1024 * 4);
    ushort* v_b = (ushort*)alloc((size_t)BS_ * 2048 * 2);
    ushort* q_b = (ushort*)alloc((size_t)BS_ * 2048 * 2);
    ushort* k_b = (ushort*)alloc((size_t)BS_ * 2048 * 2);
    ushort* ao_b = (ushort*)alloc((size_t)BS_ * 2048 * 2);
    float* cosT = (float*)alloc((size_t)S_ * 32 * 4);
    float* sinT = (float*)alloc((size_t)S_ * 32 * 4);
    // vt aliases q_pre (32MB >= 16MB needed); q_pre is dead after q_norm_rope.
    ushort* vt = (ushort*)q_pre;

    // prep
    cvt_f32_bf16<<<(BS_ * 2048 / 4 + 255) / 256, 256, 0, stream>>>(x, xb, BS_ * 2048);
    transpose_cvt<<<dim3(2048 / 32, 2048 / 32), dim3(32, 8), 0, stream>>>(wq, wq_t, 2048, 2048);
    transpose_cvt<<<dim3(512 / 32, 2048 / 32), dim3(32, 8), 0, stream>>>(w_kv_down, wkv_t, 2048, 512);
    transpose_cvt<<<dim3(1024 / 32, 512 / 32), dim3(32, 8), 0, stream>>>(w_k_rope, wkr_t, 512, 1024);
    transpose_cvt<<<dim3(1024 / 32, 512 / 32), dim3(32, 8), 0, stream>>>(w_k_nope, wkn_t, 512, 1024);
    transpose_cvt<<<dim3(2048 / 32, 512 / 32), dim3(32, 8), 0, stream>>>(wv, wv_t, 512, 2048);
    transpose_cvt<<<dim3(2048 / 32, 2048 / 32), dim3(32, 8), 0, stream>>>(wo, wo_t, 2048, 2048);
    rope_tables<<<S_ * 32 / 256, 256, 0, stream>>>(cosT, sinT);

    // projections
    gemm_bt<0><<<dim3(2048 / 128, BS_ / 128), 256, 0, stream>>>(xb, wq_t, q_pre, BS_, 2048, 2048);
    gemm_bt<1><<<dim3(512 / 128, BS_ / 128), 256, 0, stream>>>(xb, wkv_t, latent_b, BS_, 512, 2048);
    gemm_bt<0><<<dim3(1024 / 128, BS_ / 128), 256, 0, stream>>>(latent_b, wkr_t, kr_pre, BS_, 1024, 512);
    gemm_bt<0><<<dim3(1024 / 128, BS_ / 128), 256, 0, stream>>>(latent_b, wkn_t, kn_pre, BS_, 1024, 512);
    gemm_bt<1><<<dim3(2048 / 128, BS_ / 128), 256, 0, stream>>>(latent_b, wv_t, v_b, BS_, 2048, 512);

    // norms + rope (q_pre consumed here)
    q_norm_rope<<<BS_ * H_ / 4, 256, 0, stream>>>(q_pre, q_norm_w, cosT, sinT, q_b);
    k_assemble<<<BS_ * H_ / 4, 256, 0, stream>>>(kr_pre, kn_pre, k_norm_w, cosT, sinT, k_b);

    // V -> [bh][d][s] (writes over dead q_pre)
    v_transpose<<<dim3(128 / 32, 2048 / 32, B_ * H_), dim3(32, 8), 0, stream>>>(v_b, vt);

    // attention: 256 blocks, each a balanced pair of q-tiles
    attn_fwd<<<dim3(8, B_ * H_), 512, 0, stream>>>(q_b, k_b, vt, ao_b);

    // output projection
    gemm_bt<0><<<dim3(2048 / 128, BS_ / 128), 256, 0, stream>>>(ao_b, wo_t, out, BS_, 2048, 2048);
}

// Round 7
// 455.319 us; speedup vs baseline: 2.0658x; 1.0545x over previous
//
#include <hip/hip_runtime.h>
#include <hip/hip_bf16.h>
#include <math.h>

#define B_ 2
#define S_ 2048
#define D_ 2048
#define H_ 16
#define DK_ 128
#define DL_ 512
#define DR_ 64
#define BS_ (B_ * S_)   // 4096

typedef __attribute__((ext_vector_type(8))) short short8;
typedef __attribute__((ext_vector_type(4))) float f32x4;

static __device__ __forceinline__ ushort f2b(float f) {
    union { __hip_bfloat16 h; ushort u; } cvt;
    cvt.h = __float2bfloat16(f);
    return cvt.u;
}
static __device__ __forceinline__ float b2f(ushort u) {
    return __uint_as_float(((uint)u) << 16);
}

#define GLOAD_LDS16(g, l)                                                         \
    __builtin_amdgcn_global_load_lds(                                             \
        (const __attribute__((address_space(1))) void*)(g),                       \
        (__attribute__((address_space(3))) void*)(l), 16, 0, 0)

// ---------------------------------------------------------------------------
// fp32 -> bf16 elementwise convert (n divisible by 4)
// ---------------------------------------------------------------------------
__global__ __launch_bounds__(256) void cvt_f32_bf16(const float* __restrict__ in,
                                                    ushort* __restrict__ out, int n) {
    int i = (blockIdx.x * 256 + threadIdx.x) * 4;
    if (i >= n) return;
    float4 v = *(const float4*)(in + i);
    ushort4 o;
    o.x = f2b(v.x); o.y = f2b(v.y); o.z = f2b(v.z); o.w = f2b(v.w);
    *(ushort4*)(out + i) = o;
}

// ---------------------------------------------------------------------------
// fp32 (R x C) -> bf16 transposed (C x R).  grid (C/32, R/32), block (32, 8)
// ---------------------------------------------------------------------------
__global__ __launch_bounds__(256) void transpose_cvt(const float* __restrict__ in,
                                                     ushort* __restrict__ out,
                                                     int R, int C) {
    __shared__ float tile[32][33];
    int c0 = blockIdx.x * 32, r0 = blockIdx.y * 32;
    int tx = threadIdx.x, ty = threadIdx.y;
#pragma unroll
    for (int i = 0; i < 4; ++i)
        tile[ty + i * 8][tx] = in[(size_t)(r0 + ty + i * 8) * C + c0 + tx];
    __syncthreads();
#pragma unroll
    for (int i = 0; i < 4; ++i)
        out[(size_t)(c0 + ty + i * 8) * R + r0 + tx] = f2b(tile[tx][ty + i * 8]);
}

// ---------------------------------------------------------------------------
// v slice of krnv [bs][4096] (cols 2048+h*128+d) -> bf16 [b*h][d][s]
// grid (128/32, 2048/32, 32), block (32,8)
// ---------------------------------------------------------------------------
__global__ __launch_bounds__(256) void v_transpose(const ushort* __restrict__ krnv,
                                                   ushort* __restrict__ vt) {
    __shared__ ushort tile[32][34];
    const int bh = blockIdx.z, b = bh >> 4, h = bh & 15;
    const int d0 = blockIdx.x * 32, s0 = blockIdx.y * 32;
    const int tx = threadIdx.x, ty = threadIdx.y;
    const ushort* src = krnv + (size_t)(b * 2048 + s0) * 4096 + 2048 + h * 128 + d0;
#pragma unroll
    for (int i = 0; i < 4; ++i)
        tile[ty + i * 8][tx] = src[(size_t)(ty + i * 8) * 4096 + tx];  // [s][d]
    __syncthreads();
    ushort* dst = vt + ((size_t)bh * 128 + d0) * 2048 + s0;
#pragma unroll
    for (int i = 0; i < 4; ++i)
        dst[(size_t)(ty + i * 8) * 2048 + tx] = tile[tx][ty + i * 8];  // [d][s]
}

// ---------------------------------------------------------------------------
// RoPE cos/sin tables, matches jnp: freq = (1e-4)^linspace(0,1,16) ++ zeros(16)
// ---------------------------------------------------------------------------
__global__ __launch_bounds__(256) void rope_tables(float* __restrict__ cosT,
                                                   float* __restrict__ sinT) {
    int idx = blockIdx.x * 256 + threadIdx.x;
    int s = idx >> 5, j = idx & 31;
    float c = 1.f, sn = 0.f;
    if (j < 16) {
        float t = (float)j * (1.0f / 15.0f);
        float f = powf(10000.0f, -t);
        float th = (float)s * f;
        c = cosf(th);
        sn = sinf(th);
    }
    cosT[idx] = c;
    sinT[idx] = sn;
}

// ---------------------------------------------------------------------------
// bf16 GEMM, A (MxK) row-major, BT (NxK) row-major, C = A*B (MxN).
// 128x128 tile, BK=32, 4 waves in 2x2, each wave 64x64 via 4x4 16x16 frags.
// ---------------------------------------------------------------------------
template <int OUT_BF16>
__global__ __launch_bounds__(256) void gemm_bt(const ushort* __restrict__ A,
                                               const ushort* __restrict__ BT,
                                               void* __restrict__ Cv,
                                               int M, int N, int K) {
    __shared__ __align__(16) ushort As[128 * 32];
    __shared__ __align__(16) ushort Bs[128 * 32];
    const int tid = threadIdx.x;
    const int lane = tid & 63, wave = tid >> 6;
    const int wr = wave >> 1, wc = wave & 1;
    const int row0 = blockIdx.y * 128, col0 = blockIdx.x * 128;
    const int fr = lane & 15, kg = (lane >> 4) * 8;

    f32x4 acc[4][4] = {};

    const int sr = tid >> 2;
    const int sc8 = (tid & 3) * 8;
    const ushort* ga = A + (size_t)(row0 + sr) * K + sc8;
    const ushort* gb = BT + (size_t)(col0 + sr) * K + sc8;
    ushort* asDst = As + (size_t)(wave * 64) * 8;
    ushort* bsDst = Bs + (size_t)(wave * 64) * 8;

    for (int k0 = 0; k0 < K; k0 += 32) {
        GLOAD_LDS16(ga + k0, asDst);
        GLOAD_LDS16(ga + (size_t)64 * K + k0, asDst + 256 * 8);
        GLOAD_LDS16(gb + k0, bsDst);
        GLOAD_LDS16(gb + (size_t)64 * K + k0, bsDst + 256 * 8);
        __syncthreads();

        short8 af[4], bfr[4];
#pragma unroll
        for (int m = 0; m < 4; ++m)
            af[m] = *(const short8*)&As[(wr * 64 + m * 16 + fr) * 32 + kg];
#pragma unroll
        for (int n = 0; n < 4; ++n)
            bfr[n] = *(const short8*)&Bs[(wc * 64 + n * 16 + fr) * 32 + kg];
#pragma unroll
        for (int m = 0; m < 4; ++m)
#pragma unroll
            for (int n = 0; n < 4; ++n)
                acc[m][n] = __builtin_amdgcn_mfma_f32_16x16x32_bf16(af[m], bfr[n],
                                                                    acc[m][n], 0, 0, 0);
        __syncthreads();
    }

    const int rbase = row0 + wr * 64 + (lane >> 4) * 4;
    const int cbase = col0 + wc * 64 + fr;
    if constexpr (OUT_BF16) {
        ushort* C = (ushort*)Cv;
#pragma unroll
        for (int m = 0; m < 4; ++m)
#pragma unroll
            for (int n = 0; n < 4; ++n)
#pragma unroll
                for (int j = 0; j < 4; ++j)
                    C[(size_t)(rbase + m * 16 + j) * N + cbase + n * 16] = f2b(acc[m][n][j]);
    } else {
        float* C = (float*)Cv;
#pragma unroll
        for (int m = 0; m < 4; ++m)
#pragma unroll
            for (int n = 0; n < 4; ++n)
#pragma unroll
                for (int j = 0; j < 4; ++j)
                    C[(size_t)(rbase + m * 16 + j) * N + cbase + n * 16] = acc[m][n][j];
    }
}

// ---------------------------------------------------------------------------
// q: rmsnorm then RoPE on first 64 dims; bf16 in, bf16 out pre-scaled 1/sqrt(128)
// ---------------------------------------------------------------------------
__global__ __launch_bounds__(256) void q_norm_rope(const ushort* __restrict__ qp,
                                                   const float* __restrict__ w,
                                                   const float* __restrict__ cosT,
                                                   const float* __restrict__ sinT,
                                                   ushort* __restrict__ qb) {
    const int lane = threadIdx.x & 63, wave = threadIdx.x >> 6;
    const int rowId = blockIdx.x * 4 + wave;
    const int bs = rowId >> 4, h = rowId & 15;
    const int s = bs & (S_ - 1);
    const float scale = 0.08838834764831845f;  // 1/sqrt(128) folded into q
    const ushort* src = qp + (size_t)bs * 2048 + h * 128;
    float e0 = b2f(src[lane]), e1 = b2f(src[64 + lane]);
    float ss = e0 * e0 + e1 * e1;
#pragma unroll
    for (int m = 1; m < 64; m <<= 1) ss += __shfl_xor(ss, m, 64);
    float r = rsqrtf(ss * (1.0f / 128.0f) + 1e-6f);
    float xn0 = e0 * r * w[lane];
    float xn1 = e1 * r * w[64 + lane];
    int j = lane & 31;
    float c = cosT[s * 32 + j], sn = sinT[s * 32 + j];
    float p = __shfl_xor(xn0, 32, 64);
    float y0 = (lane < 32) ? (xn0 * c + p * sn) : (-p * sn + xn0 * c);
    ushort* dst = qb + (size_t)bs * 2048 + h * 128;
    dst[lane] = f2b(y0 * scale);
    dst[64 + lane] = f2b(xn1 * scale);
}

// ---------------------------------------------------------------------------
// k: RoPE(k_rope) ++ k_nope, then rmsnorm over 128. 1 wave = 1 row.
// reads fused krnv [bs][4096]: cols 0..1023 k_rope, 1024..2047 k_nope (bf16)
// ---------------------------------------------------------------------------
__global__ __launch_bounds__(256) void k_assemble(const ushort* __restrict__ krnv,
                                                  const float* __restrict__ w,
                                                  const float* __restrict__ cosT,
                                                  const float* __restrict__ sinT,
                                                  ushort* __restrict__ kb) {
    const int lane = threadIdx.x & 63, wave = threadIdx.x >> 6;
    const int rowId = blockIdx.x * 4 + wave;
    const int bs = rowId >> 4, h = rowId & 15;
    const int s = bs & (S_ - 1);
    float e0 = b2f(krnv[(size_t)bs * 4096 + h * 64 + lane]);
    float e1 = b2f(krnv[(size_t)bs * 4096 + 1024 + h * 64 + lane]);
    int j = lane & 31;
    float c = cosT[s * 32 + j], sn = sinT[s * 32 + j];
    float p = __shfl_xor(e0, 32, 64);
    float y0 = (lane < 32) ? (e0 * c + p * sn) : (-p * sn + e0 * c);
    float ss = y0 * y0 + e1 * e1;
#pragma unroll
    for (int m = 1; m < 64; m <<= 1) ss += __shfl_xor(ss, m, 64);
    float r = rsqrtf(ss * (1.0f / 128.0f) + 1e-6f);
    ushort* dst = kb + (size_t)bs * 2048 + h * 128;
    dst[lane] = f2b(y0 * r * w[lane]);
    dst[64 + lane] = f2b(e1 * r * w[64 + lane]);
}

// ---------------------------------------------------------------------------
// causal flash attention. grid (8, 32), block 512 (8 waves x 16 q rows).
// XCD-aware remap: blockIdx.x (=XCD on MI355X round-robin) picks the bh group
// (bh = x*4 + (y&3)) so one XCD's 32 blocks share only 4 heads' K/V (4MB = L2).
// qpair = y>>2; block processes q-tiles {15-qp, qp} -> 36 KV iters (balanced).
// K and V^T staged in LDS (double-buffered, global_load_lds w16, subtiled
// layout -> conflict-free ds_read_b128), prefetched one tile ahead.
// P: per-wave 16x64, 16B-granule XOR swizzle key (row>>1)&7 (write: 32-bank
// spread 2/bank = free). T13 defer-max skip; T5 setprio around MFMA clusters.
// Total LDS = 80KB -> 2 blocks/CU.
// ---------------------------------------------------------------------------
__global__ __launch_bounds__(512) void attn_fwd(const ushort* __restrict__ Q,
                                                const ushort* __restrict__ Kb,
                                                const ushort* __restrict__ Vt,
                                                ushort* __restrict__ Ob) {
    __shared__ __align__(16) ushort Kls[2][8192];   // 2 x 16KB
    __shared__ __align__(16) ushort Vls[2][8192];   // 2 x 16KB
    __shared__ __align__(16) ushort Pls[8][1024];   // per-wave P, 16 x 64 swizzled
    const int tid = threadIdx.x, lane = tid & 63, wave = tid >> 6;
    const int bh = (int)blockIdx.x * 4 + ((int)blockIdx.y & 3);   // XCD grouping
    const int qp = (int)blockIdx.y >> 2;
    const int b = bh >> 4, h = bh & 15;
    const int fr = lane & 15, g = lane >> 4;        // MFMA fragment coords
    const int sfr = lane >> 2, sg = lane & 3;       // staging coords

    const ushort* qbase = Q + (size_t)(b * S_) * 2048 + h * 128;
    const ushort* kbase = Kb + (size_t)(b * S_) * 2048 + h * 128;
    const ushort* vtbase = Vt + (size_t)bh * 128 * 2048;
    ushort* myP = Pls[wave];

    auto stage = [&](int kt0, int bufi) {
#pragma unroll
        for (int i = 0; i < 2; ++i) {
            const int si = wave * 2 + i;
            GLOAD_LDS16(kbase + (size_t)(kt0 + (si >> 2) * 16 + sfr) * 2048 +
                            (si & 3) * 32 + sg * 8,
                        &Kls[bufi][si * 512]);
            GLOAD_LDS16(vtbase + (size_t)((si >> 1) * 16 + sfr) * 2048 + kt0 +
                            (si & 1) * 32 + sg * 8,
                        &Vls[bufi][si * 512]);
        }
    };

#pragma unroll 1
    for (int pi = 0; pi < 2; ++pi) {
        const int qi = pi ? qp : 15 - qp;  // heavy first
        const int q0 = qi * 128;
        const int nt = 2 * qi + 2;

        // Q fragments for this pass: rows q0 + wave*16 + fr
        short8 qf[4];
        const ushort* qrow = qbase + (size_t)(q0 + wave * 16 + fr) * 2048;
#pragma unroll
        for (int kb = 0; kb < 4; ++kb) qf[kb] = *(const short8*)(qrow + kb * 32 + g * 8);

        f32x4 Oacc[8] = {};
        float mrow[4], lrow[4];
#pragma unroll
        for (int j = 0; j < 4; ++j) { mrow[j] = -1e30f; lrow[j] = 0.f; }

        stage(0, 0);
        for (int t = 0; t < nt; ++t) {
            __syncthreads();                     // drains vmcnt: tile t visible
            if (t + 1 < nt) stage((t + 1) * 64, (t + 1) & 1);
            const ushort* Kc = Kls[t & 1];
            const ushort* Vc = Vls[t & 1];
            const int kt0 = t * 64;
            // ---- QK^T
            f32x4 sc[4] = {};
            __builtin_amdgcn_s_setprio(1);
#pragma unroll
            for (int n = 0; n < 4; ++n)
#pragma unroll
                for (int kb = 0; kb < 4; ++kb) {
                    short8 kf = *(const short8*)&Kc[(n * 4 + kb) * 512 + fr * 32 + g * 8];
                    sc[n] = __builtin_amdgcn_mfma_f32_16x16x32_bf16(qf[kb], kf, sc[n], 0, 0, 0);
                }
            __builtin_amdgcn_s_setprio(0);
            // ---- causal mask (only last 2 tiles can touch the diagonal)
            if (t >= nt - 2) {
#pragma unroll
                for (int n = 0; n < 4; ++n) {
                    int kpos = kt0 + n * 16 + fr;
#pragma unroll
                    for (int j = 0; j < 4; ++j) {
                        int qr = q0 + wave * 16 + g * 4 + j;
                        if (kpos > qr) sc[n][j] = -1e30f;
                    }
                }
            }
            // ---- online softmax (reduce over fr: 4 rounds of 16-wide xor)
            float tmax[4];
#pragma unroll
            for (int j = 0; j < 4; ++j)
                tmax[j] = fmaxf(fmaxf(sc[0][j], sc[1][j]), fmaxf(sc[2][j], sc[3][j]));
#pragma unroll
            for (int m = 1; m < 16; m <<= 1)
#pragma unroll
                for (int j = 0; j < 4; ++j) tmax[j] = fmaxf(tmax[j], __shfl_xor(tmax[j], m, 64));
            // T13 defer-max: skip rescale when tile max within THR of running max
            float dm = fmaxf(fmaxf(tmax[0] - mrow[0], tmax[1] - mrow[1]),
                             fmaxf(tmax[2] - mrow[2], tmax[3] - mrow[3]));
            if (!__all(dm <= 8.0f)) {
                float alpha[4];
#pragma unroll
                for (int j = 0; j < 4; ++j) {
                    float mn = fmaxf(mrow[j], tmax[j]);
                    alpha[j] = __expf(mrow[j] - mn);
                    mrow[j] = mn;
                    lrow[j] *= alpha[j];
                }
#pragma unroll
                for (int n8 = 0; n8 < 8; ++n8)
#pragma unroll
                    for (int j = 0; j < 4; ++j) Oacc[n8][j] *= alpha[j];
            }
            float rsum[4] = {0.f, 0.f, 0.f, 0.f};
#pragma unroll
            for (int n = 0; n < 4; ++n)
#pragma unroll
                for (int j = 0; j < 4; ++j) {
                    float pv = __expf(sc[n][j] - mrow[j]);
                    sc[n][j] = pv;
                    rsum[j] += pv;
                }
#pragma unroll
            for (int m = 1; m < 16; m <<= 1)
#pragma unroll
                for (int j = 0; j < 4; ++j) rsum[j] += __shfl_xor(rsum[j], m, 64);
#pragma unroll
            for (int j = 0; j < 4; ++j) lrow[j] += rsum[j];
            // ---- P -> per-wave LDS, row q = g*4+j, granule-XOR key (q>>1)&7
#pragma unroll
            for (int n = 0; n < 4; ++n)
#pragma unroll
                for (int j = 0; j < 4; ++j) {
                    int q = g * 4 + j;
                    int cg = n * 2 + (fr >> 3);                       // logical granule
                    int cs = (((cg ^ (q >> 1)) & 7) << 3) | (fr & 7); // swizzled offset
                    myP[q * 64 + cs] = f2b(sc[n][j]);
                }
            // ---- PV (A = P rows, B = V^T subtiles; wave-private P: lgkm only)
            short8 pa[2];
#pragma unroll
            for (int ks = 0; ks < 2; ++ks) {
                int pg = ((ks * 4 + g) ^ (fr >> 1)) & 7;              // phys granule
                pa[ks] = *(const short8*)&myP[fr * 64 + (pg << 3)];
            }
            __builtin_amdgcn_s_setprio(1);
#pragma unroll
            for (int n8 = 0; n8 < 8; ++n8)
#pragma unroll
                for (int ks = 0; ks < 2; ++ks) {
                    short8 vf = *(const short8*)&Vc[(n8 * 2 + ks) * 512 + fr * 32 + g * 8];
                    Oacc[n8] = __builtin_amdgcn_mfma_f32_16x16x32_bf16(pa[ks], vf, Oacc[n8], 0, 0, 0);
                }
            __builtin_amdgcn_s_setprio(0);
        }
        // ---- epilogue
#pragma unroll
        for (int j = 0; j < 4; ++j) {
            int qr = q0 + wave * 16 + g * 4 + j;
            float inv = 1.0f / lrow[j];
            ushort* orow = Ob + (size_t)(b * S_ + qr) * 2048 + h * 128;
#pragma unroll
            for (int n8 = 0; n8 < 8; ++n8) orow[n8 * 16 + fr] = f2b(Oacc[n8][j] * inv);
        }
        __syncthreads();  // protect LDS buffers before next pass restages
    }
}

// ---------------------------------------------------------------------------
extern "C" void kernel_launch(void* const* d_in, const int* in_sizes, int n_in,
                              void* d_out, int out_size, void* d_ws, size_t ws_size,
                              hipStream_t stream) {
    (void)in_sizes; (void)n_in; (void)out_size; (void)ws_size;
    const float* x = (const float*)d_in[0];
    const float* wq = (const float*)d_in[1];
    const float* w_kv_down = (const float*)d_in[2];
    const float* w_k_rope = (const float*)d_in[3];
    const float* w_k_nope = (const float*)d_in[4];
    const float* wv = (const float*)d_in[5];
    const float* wo = (const float*)d_in[6];
    const float* q_norm_w = (const float*)d_in[7];
    const float* k_norm_w = (const float*)d_in[8];
    float* out = (float*)d_out;

    char* ws = (char*)d_ws;
    size_t off = 0;
    auto alloc = [&](size_t bytes) {
        off = (off + 255) & ~(size_t)255;
        void* p = ws + off;
        off += bytes;
        return p;
    };
    ushort* xb = (ushort*)alloc((size_t)BS_ * 2048 * 2);
    ushort* wq_t = (ushort*)alloc((size_t)2048 * 2048 * 2);
    ushort* wkv_t = (ushort*)alloc((size_t)512 * 2048 * 2);
    ushort* wkrnv_t = (ushort*)alloc((size_t)4096 * 512 * 2);   // [kr 1024][kn 1024][v 2048] x 512
    ushort* wo_t = (ushort*)alloc((size_t)2048 * 2048 * 2);
    ushort* q_pre_b = (ushort*)alloc((size_t)BS_ * 2048 * 2);
    ushort* latent_b = (ushort*)alloc((size_t)BS_ * 512 * 2);
    ushort* krnv_b = (ushort*)alloc((size_t)BS_ * 4096 * 2);
    ushort* q_b = (ushort*)alloc((size_t)BS_ * 2048 * 2);
    ushort* k_b = (ushort*)alloc((size_t)BS_ * 2048 * 2);
    ushort* vt = (ushort*)alloc((size_t)BS_ * 2048 * 2);
    ushort* ao_b = (ushort*)alloc((size_t)BS_ * 2048 * 2);
    float* cosT = (float*)alloc((size_t)S_ * 32 * 4);
    float* sinT = (float*)alloc((size_t)S_ * 32 * 4);

    // prep
    cvt_f32_bf16<<<(BS_ * 2048 / 4 + 255) / 256, 256, 0, stream>>>(x, xb, BS_ * 2048);
    transpose_cvt<<<dim3(2048 / 32, 2048 / 32), dim3(32, 8), 0, stream>>>(wq, wq_t, 2048, 2048);
    transpose_cvt<<<dim3(512 / 32, 2048 / 32), dim3(32, 8), 0, stream>>>(w_kv_down, wkv_t, 2048, 512);
    transpose_cvt<<<dim3(1024 / 32, 512 / 32), dim3(32, 8), 0, stream>>>(w_k_rope, wkrnv_t, 512, 1024);
    transpose_cvt<<<dim3(1024 / 32, 512 / 32), dim3(32, 8), 0, stream>>>(w_k_nope, wkrnv_t + (size_t)1024 * 512, 512, 1024);
    transpose_cvt<<<dim3(2048 / 32, 512 / 32), dim3(32, 8), 0, stream>>>(wv, wkrnv_t + (size_t)2048 * 512, 512, 2048);
    transpose_cvt<<<dim3(2048 / 32, 2048 / 32), dim3(32, 8), 0, stream>>>(wo, wo_t, 2048, 2048);
    rope_tables<<<S_ * 32 / 256, 256, 0, stream>>>(cosT, sinT);

    // projections
    gemm_bt<1><<<dim3(2048 / 128, BS_ / 128), 256, 0, stream>>>(xb, wq_t, q_pre_b, BS_, 2048, 2048);
    gemm_bt<1><<<dim3(512 / 128, BS_ / 128), 256, 0, stream>>>(xb, wkv_t, latent_b, BS_, 512, 2048);
    gemm_bt<1><<<dim3(4096 / 128, BS_ / 128), 256, 0, stream>>>(latent_b, wkrnv_t, krnv_b, BS_, 4096, 512);

    // norms + rope
    q_norm_rope<<<BS_ * H_ / 4, 256, 0, stream>>>(q_pre_b, q_norm_w, cosT, sinT, q_b);
    k_assemble<<<BS_ * H_ / 4, 256, 0, stream>>>(krnv_b, k_norm_w, cosT, sinT, k_b);

    // V -> [bh][d][s]
    v_transpose<<<dim3(128 / 32, 2048 / 32, B_ * H_), dim3(32, 8), 0, stream>>>(krnv_b, vt);

    // attention: 256 blocks (XCD-grouped bh), each a balanced pair of q-tiles
    attn_fwd<<<dim3(8, B_ * H_), 512, 0, stream>>>(q_b, k_b, vt, ao_b);

    // output projection
    gemm_bt<0><<<dim3(2048 / 128, BS_ / 128), 256, 0, stream>>>(ao_b, wo_t, out, BS_, 2048, 2048);
}

// Round 8
// 395.835 us; speedup vs baseline: 2.3763x; 1.1503x over previous
//
#include <hip/hip_runtime.h>
#include <hip/hip_bf16.h>
#include <math.h>

#define B_ 2
#define S_ 2048
#define D_ 2048
#define H_ 16
#define DK_ 128
#define DL_ 512
#define DR_ 64
#define BS_ (B_ * S_)   // 4096

typedef __attribute__((ext_vector_type(8))) short short8;
typedef __attribute__((ext_vector_type(4))) float f32x4;

static __device__ __forceinline__ ushort f2b(float f) {
    union { __hip_bfloat16 h; ushort u; } cvt;
    cvt.h = __float2bfloat16(f);
    return cvt.u;
}
static __device__ __forceinline__ float b2f(ushort u) {
    return __uint_as_float(((uint)u) << 16);
}

#define GLOAD_LDS16(g, l)                                                         \
    __builtin_amdgcn_global_load_lds(                                             \
        (const __attribute__((address_space(1))) void*)(g),                       \
        (__attribute__((address_space(3))) void*)(l), 16, 0, 0)

// ---------------------------------------------------------------------------
// fused prep: [0,8192) x->bf16 | transposes (f32 RxC -> bf16 CxR) | rope tables
// block = 256 threads. Transpose branch uses tx=tid&31, ty=tid>>5 (32x8).
// ---------------------------------------------------------------------------
static __device__ __forceinline__ void tr_cvt(const float* __restrict__ in,
                                              ushort* __restrict__ out,
                                              int R, int C, int bx, int by,
                                              float (*tile)[33]) {
    const int tx = threadIdx.x & 31, ty = threadIdx.x >> 5;
    const int c0 = bx * 32, r0 = by * 32;
#pragma unroll
    for (int i = 0; i < 4; ++i)
        tile[ty + i * 8][tx] = in[(size_t)(r0 + ty + i * 8) * C + c0 + tx];
    __syncthreads();
#pragma unroll
    for (int i = 0; i < 4; ++i)
        out[(size_t)(c0 + ty + i * 8) * R + r0 + tx] = f2b(tile[tx][ty + i * 8]);
}

__global__ __launch_bounds__(256) void prep(const float* __restrict__ x,
                                            ushort* __restrict__ xb,
                                            const float* __restrict__ wq,
                                            ushort* __restrict__ wq_t,
                                            const float* __restrict__ wkv,
                                            ushort* __restrict__ wkv_t,
                                            const float* __restrict__ wkr,
                                            const float* __restrict__ wkn,
                                            const float* __restrict__ wv,
                                            ushort* __restrict__ wkrnv_t,
                                            const float* __restrict__ wo,
                                            ushort* __restrict__ wo_t,
                                            float* __restrict__ cosT,
                                            float* __restrict__ sinT) {
    __shared__ float tile[32][33];
    const int id = blockIdx.x, tid = threadIdx.x;
    if (id < 8192) {                                   // x -> bf16
        int i = (id * 256 + tid) * 4;
        float4 v = *(const float4*)(x + i);
        ushort4 o;
        o.x = f2b(v.x); o.y = f2b(v.y); o.z = f2b(v.z); o.w = f2b(v.w);
        *(ushort4*)(xb + i) = o;
    } else if (id < 12288) {                           // wq^T (64x64)
        int l = id - 8192;
        tr_cvt(wq, wq_t, 2048, 2048, l & 63, l >> 6, tile);
    } else if (id < 13312) {                           // wkv^T (16x64)
        int l = id - 12288;
        tr_cvt(wkv, wkv_t, 2048, 512, l & 15, l >> 4, tile);
    } else if (id < 13824) {                           // wkr^T (32x16)
        int l = id - 13312;
        tr_cvt(wkr, wkrnv_t, 512, 1024, l & 31, l >> 5, tile);
    } else if (id < 14336) {                           // wkn^T
        int l = id - 13824;
        tr_cvt(wkn, wkrnv_t + (size_t)1024 * 512, 512, 1024, l & 31, l >> 5, tile);
    } else if (id < 15360) {                           // wv^T (64x16)
        int l = id - 14336;
        tr_cvt(wv, wkrnv_t + (size_t)2048 * 512, 512, 2048, l & 63, l >> 6, tile);
    } else if (id < 19456) {                           // wo^T (64x64)
        int l = id - 15360;
        tr_cvt(wo, wo_t, 2048, 2048, l & 63, l >> 6, tile);
    } else {                                           // rope tables
        int idx = (id - 19456) * 256 + tid;
        int s = idx >> 5, j = idx & 31;
        float c = 1.f, sn = 0.f;
        if (j < 16) {
            float t = (float)j * (1.0f / 15.0f);
            float f = powf(10000.0f, -t);
            float th = (float)s * f;
            c = cosf(th);
            sn = sinf(th);
        }
        cosT[idx] = c;
        sinT[idx] = sn;
    }
}

// ---------------------------------------------------------------------------
// bf16 GEMM body (m97 structure). A (MxK) rm, BT (NxK) rm, C = A*B.
// 128x128 tile, BK=32, 4 waves 2x2, 4x4 16x16 frags / wave.
// ---------------------------------------------------------------------------
template <int OUT_BF16>
static __device__ __forceinline__ void gemm_body(const ushort* __restrict__ A,
                                                 const ushort* __restrict__ BT,
                                                 void* __restrict__ Cv,
                                                 int N, int K, int row0, int col0,
                                                 ushort* As, ushort* Bs) {
    const int tid = threadIdx.x;
    const int lane = tid & 63, wave = tid >> 6;
    const int wr = wave >> 1, wc = wave & 1;
    const int fr = lane & 15, kg = (lane >> 4) * 8;

    f32x4 acc[4][4] = {};

    const int sr = tid >> 2;
    const int sc8 = (tid & 3) * 8;
    const ushort* ga = A + (size_t)(row0 + sr) * K + sc8;
    const ushort* gb = BT + (size_t)(col0 + sr) * K + sc8;
    ushort* asDst = As + (size_t)(wave * 64) * 8;
    ushort* bsDst = Bs + (size_t)(wave * 64) * 8;

    for (int k0 = 0; k0 < K; k0 += 32) {
        GLOAD_LDS16(ga + k0, asDst);
        GLOAD_LDS16(ga + (size_t)64 * K + k0, asDst + 256 * 8);
        GLOAD_LDS16(gb + k0, bsDst);
        GLOAD_LDS16(gb + (size_t)64 * K + k0, bsDst + 256 * 8);
        __syncthreads();

        short8 af[4], bfr[4];
#pragma unroll
        for (int m = 0; m < 4; ++m)
            af[m] = *(const short8*)&As[(wr * 64 + m * 16 + fr) * 32 + kg];
#pragma unroll
        for (int n = 0; n < 4; ++n)
            bfr[n] = *(const short8*)&Bs[(wc * 64 + n * 16 + fr) * 32 + kg];
#pragma unroll
        for (int m = 0; m < 4; ++m)
#pragma unroll
            for (int n = 0; n < 4; ++n)
                acc[m][n] = __builtin_amdgcn_mfma_f32_16x16x32_bf16(af[m], bfr[n],
                                                                    acc[m][n], 0, 0, 0);
        __syncthreads();
    }

    const int rbase = row0 + wr * 64 + (lane >> 4) * 4;
    const int cbase = col0 + wc * 64 + fr;
    if constexpr (OUT_BF16) {
        ushort* C = (ushort*)Cv;
#pragma unroll
        for (int m = 0; m < 4; ++m)
#pragma unroll
            for (int n = 0; n < 4; ++n)
#pragma unroll
                for (int j = 0; j < 4; ++j)
                    C[(size_t)(rbase + m * 16 + j) * N + cbase + n * 16] = f2b(acc[m][n][j]);
    } else {
        float* C = (float*)Cv;
#pragma unroll
        for (int m = 0; m < 4; ++m)
#pragma unroll
            for (int n = 0; n < 4; ++n)
#pragma unroll
                for (int j = 0; j < 4; ++j)
                    C[(size_t)(rbase + m * 16 + j) * N + cbase + n * 16] = acc[m][n][j];
    }
}

template <int OUT_BF16>
__global__ __launch_bounds__(256) void gemm_bt(const ushort* __restrict__ A,
                                               const ushort* __restrict__ BT,
                                               void* __restrict__ Cv,
                                               int N, int K) {
    __shared__ __align__(16) ushort As[128 * 32];
    __shared__ __align__(16) ushort Bs[128 * 32];
    gemm_body<OUT_BF16>(A, BT, Cv, N, K, blockIdx.y * 128, blockIdx.x * 128, As, Bs);
}

// q-proj (N=2048) and latent-proj (N=512) fused: grid (20, 32)
__global__ __launch_bounds__(256) void gemm_qlat(const ushort* __restrict__ A,
                                                 const ushort* __restrict__ wq_t,
                                                 const ushort* __restrict__ wkv_t,
                                                 ushort* __restrict__ qp,
                                                 ushort* __restrict__ lat) {
    __shared__ __align__(16) ushort As[128 * 32];
    __shared__ __align__(16) ushort Bs[128 * 32];
    const int bx = blockIdx.x;
    if (bx < 16)
        gemm_body<1>(A, wq_t, qp, 2048, 2048, blockIdx.y * 128, bx * 128, As, Bs);
    else
        gemm_body<1>(A, wkv_t, lat, 512, 2048, blockIdx.y * 128, (bx - 16) * 128, As, Bs);
}

// ---------------------------------------------------------------------------
// fused epilogue: [0,16384) q rmsnorm+rope | [16384,32768) k assemble |
// [32768,40960) v transpose. 256 threads.
// ---------------------------------------------------------------------------
__global__ __launch_bounds__(256) void epi(const ushort* __restrict__ qp,
                                           const ushort* __restrict__ krnv,
                                           const float* __restrict__ qw,
                                           const float* __restrict__ kw,
                                           const float* __restrict__ cosT,
                                           const float* __restrict__ sinT,
                                           ushort* __restrict__ qb,
                                           ushort* __restrict__ kb,
                                           ushort* __restrict__ vt) {
    __shared__ ushort tile[32][34];
    const int id = blockIdx.x;
    const int lane = threadIdx.x & 63, wave = threadIdx.x >> 6;
    if (id < 16384) {            // ---- q: rmsnorm + rope, pre-scaled
        const int rowId = id * 4 + wave;
        const int bs = rowId >> 4, h = rowId & 15;
        const int s = bs & (S_ - 1);
        const float scale = 0.08838834764831845f;
        const ushort* src = qp + (size_t)bs * 2048 + h * 128;
        float e0 = b2f(src[lane]), e1 = b2f(src[64 + lane]);
        float ss = e0 * e0 + e1 * e1;
#pragma unroll
        for (int m = 1; m < 64; m <<= 1) ss += __shfl_xor(ss, m, 64);
        float r = rsqrtf(ss * (1.0f / 128.0f) + 1e-6f);
        float xn0 = e0 * r * qw[lane];
        float xn1 = e1 * r * qw[64 + lane];
        int j = lane & 31;
        float c = cosT[s * 32 + j], sn = sinT[s * 32 + j];
        float p = __shfl_xor(xn0, 32, 64);
        float y0 = (lane < 32) ? (xn0 * c + p * sn) : (-p * sn + xn0 * c);
        ushort* dst = qb + (size_t)bs * 2048 + h * 128;
        dst[lane] = f2b(y0 * scale);
        dst[64 + lane] = f2b(xn1 * scale);
    } else if (id < 32768) {     // ---- k: rope(k_rope) ++ k_nope, rmsnorm
        const int rowId = (id - 16384) * 4 + wave;
        const int bs = rowId >> 4, h = rowId & 15;
        const int s = bs & (S_ - 1);
        float e0 = b2f(krnv[(size_t)bs * 4096 + h * 64 + lane]);
        float e1 = b2f(krnv[(size_t)bs * 4096 + 1024 + h * 64 + lane]);
        int j = lane & 31;
        float c = cosT[s * 32 + j], sn = sinT[s * 32 + j];
        float p = __shfl_xor(e0, 32, 64);
        float y0 = (lane < 32) ? (e0 * c + p * sn) : (-p * sn + e0 * c);
        float ss = y0 * y0 + e1 * e1;
#pragma unroll
        for (int m = 1; m < 64; m <<= 1) ss += __shfl_xor(ss, m, 64);
        float r = rsqrtf(ss * (1.0f / 128.0f) + 1e-6f);
        ushort* dst = kb + (size_t)bs * 2048 + h * 128;
        dst[lane] = f2b(y0 * r * kw[lane]);
        dst[64 + lane] = f2b(e1 * r * kw[64 + lane]);
    } else {                     // ---- v slice of krnv -> [bh][d][s]
        const int l = id - 32768;
        const int bx = l & 3, by = (l >> 2) & 63, bh = l >> 8;
        const int b = bh >> 4, h = bh & 15;
        const int d0 = bx * 32, s0 = by * 32;
        const int tx = threadIdx.x & 31, ty = threadIdx.x >> 5;
        const ushort* src = krnv + (size_t)(b * 2048 + s0) * 4096 + 2048 + h * 128 + d0;
#pragma unroll
        for (int i = 0; i < 4; ++i)
            tile[ty + i * 8][tx] = src[(size_t)(ty + i * 8) * 4096 + tx];
        __syncthreads();
        ushort* dst = vt + ((size_t)bh * 128 + d0) * 2048 + s0;
#pragma unroll
        for (int i = 0; i < 4; ++i)
            dst[(size_t)(ty + i * 8) * 2048 + tx] = tile[tx][ty + i * 8];
    }
}

// ---------------------------------------------------------------------------
// causal flash attention. grid (32, 16), block 512 (8 waves x 16 q rows).
// One 128-row q-tile per block (heavy-first: y=0 -> qi=15). 512 blocks ->
// 2 blocks/CU (LDS 80KB). XCD grouping: bh=(bhx&7)*4+(bhx>>3) so each XCD's
// blocks share 4 heads' K/V (4MB = its L2). KV tile = 64, K/V^T double-
// buffered via global_load_lds w16 subtiled layout; P per-wave 16x64 swizzled.
// ---------------------------------------------------------------------------
__global__ __launch_bounds__(512) void attn_fwd(const ushort* __restrict__ Q,
                                                const ushort* __restrict__ Kb,
                                                const ushort* __restrict__ Vt,
                                                ushort* __restrict__ Ob) {
    __shared__ __align__(16) ushort Kls[2][8192];   // 2 x 16KB
    __shared__ __align__(16) ushort Vls[2][8192];   // 2 x 16KB
    __shared__ __align__(16) ushort Pls[8][1024];   // per-wave P, 16 x 64 swizzled
    const int tid = threadIdx.x, lane = tid & 63, wave = tid >> 6;
    const int bhx = blockIdx.x;
    const int bh = (bhx & 7) * 4 + (bhx >> 3);      // XCD grouping
    const int qi = 15 - (int)blockIdx.y;            // heavy-first
    const int b = bh >> 4, h = bh & 15;
    const int fr = lane & 15, g = lane >> 4;        // MFMA fragment coords
    const int sfr = lane >> 2, sg = lane & 3;       // staging coords

    const ushort* qbase = Q + (size_t)(b * S_) * 2048 + h * 128;
    const ushort* kbase = Kb + (size_t)(b * S_) * 2048 + h * 128;
    const ushort* vtbase = Vt + (size_t)bh * 128 * 2048;
    ushort* myP = Pls[wave];

    auto stage = [&](int kt0, int bufi) {
#pragma unroll
        for (int i = 0; i < 2; ++i) {
            const int si = wave * 2 + i;
            GLOAD_LDS16(kbase + (size_t)(kt0 + (si >> 2) * 16 + sfr) * 2048 +
                            (si & 3) * 32 + sg * 8,
                        &Kls[bufi][si * 512]);
            GLOAD_LDS16(vtbase + (size_t)((si >> 1) * 16 + sfr) * 2048 + kt0 +
                            (si & 1) * 32 + sg * 8,
                        &Vls[bufi][si * 512]);
        }
    };

    const int q0 = qi * 128;
    const int nt = 2 * qi + 2;

    // Q fragments: rows q0 + wave*16 + fr
    short8 qf[4];
    const ushort* qrow = qbase + (size_t)(q0 + wave * 16 + fr) * 2048;
#pragma unroll
    for (int kb = 0; kb < 4; ++kb) qf[kb] = *(const short8*)(qrow + kb * 32 + g * 8);

    f32x4 Oacc[8] = {};
    float mrow[4], lrow[4];
#pragma unroll
    for (int j = 0; j < 4; ++j) { mrow[j] = -1e30f; lrow[j] = 0.f; }

    stage(0, 0);
    for (int t = 0; t < nt; ++t) {
        __syncthreads();                     // drains vmcnt: tile t visible
        if (t + 1 < nt) stage((t + 1) * 64, (t + 1) & 1);
        const ushort* Kc = Kls[t & 1];
        const ushort* Vc = Vls[t & 1];
        const int kt0 = t * 64;
        // ---- QK^T
        f32x4 sc[4] = {};
        __builtin_amdgcn_s_setprio(1);
#pragma unroll
        for (int n = 0; n < 4; ++n)
#pragma unroll
            for (int kb = 0; kb < 4; ++kb) {
                short8 kf = *(const short8*)&Kc[(n * 4 + kb) * 512 + fr * 32 + g * 8];
                sc[n] = __builtin_amdgcn_mfma_f32_16x16x32_bf16(qf[kb], kf, sc[n], 0, 0, 0);
            }
        __builtin_amdgcn_s_setprio(0);
        // ---- causal mask (only last 2 tiles can touch the diagonal)
        if (t >= nt - 2) {
#pragma unroll
            for (int n = 0; n < 4; ++n) {
                int kpos = kt0 + n * 16 + fr;
#pragma unroll
                for (int j = 0; j < 4; ++j) {
                    int qr = q0 + wave * 16 + g * 4 + j;
                    if (kpos > qr) sc[n][j] = -1e30f;
                }
            }
        }
        // ---- online softmax
        float tmax[4];
#pragma unroll
        for (int j = 0; j < 4; ++j)
            tmax[j] = fmaxf(fmaxf(sc[0][j], sc[1][j]), fmaxf(sc[2][j], sc[3][j]));
#pragma unroll
        for (int m = 1; m < 16; m <<= 1)
#pragma unroll
            for (int j = 0; j < 4; ++j) tmax[j] = fmaxf(tmax[j], __shfl_xor(tmax[j], m, 64));
        float dm = fmaxf(fmaxf(tmax[0] - mrow[0], tmax[1] - mrow[1]),
                         fmaxf(tmax[2] - mrow[2], tmax[3] - mrow[3]));
        if (!__all(dm <= 8.0f)) {           // T13 defer-max
            float alpha[4];
#pragma unroll
            for (int j = 0; j < 4; ++j) {
                float mn = fmaxf(mrow[j], tmax[j]);
                alpha[j] = __expf(mrow[j] - mn);
                mrow[j] = mn;
                lrow[j] *= alpha[j];
            }
#pragma unroll
            for (int n8 = 0; n8 < 8; ++n8)
#pragma unroll
                for (int j = 0; j < 4; ++j) Oacc[n8][j] *= alpha[j];
        }
        float rsum[4] = {0.f, 0.f, 0.f, 0.f};
#pragma unroll
        for (int n = 0; n < 4; ++n)
#pragma unroll
            for (int j = 0; j < 4; ++j) {
                float pv = __expf(sc[n][j] - mrow[j]);
                sc[n][j] = pv;
                rsum[j] += pv;
            }
#pragma unroll
        for (int m = 1; m < 16; m <<= 1)
#pragma unroll
            for (int j = 0; j < 4; ++j) rsum[j] += __shfl_xor(rsum[j], m, 64);
#pragma unroll
        for (int j = 0; j < 4; ++j) lrow[j] += rsum[j];
        // ---- P -> per-wave LDS, row q = g*4+j, granule-XOR key (q>>1)&7
#pragma unroll
        for (int n = 0; n < 4; ++n)
#pragma unroll
            for (int j = 0; j < 4; ++j) {
                int q = g * 4 + j;
                int cg = n * 2 + (fr >> 3);
                int cs = (((cg ^ (q >> 1)) & 7) << 3) | (fr & 7);
                myP[q * 64 + cs] = f2b(sc[n][j]);
            }
        // ---- PV
        short8 pa[2];
#pragma unroll
        for (int ks = 0; ks < 2; ++ks) {
            int pg = ((ks * 4 + g) ^ (fr >> 1)) & 7;
            pa[ks] = *(const short8*)&myP[fr * 64 + (pg << 3)];
        }
        __builtin_amdgcn_s_setprio(1);
#pragma unroll
        for (int n8 = 0; n8 < 8; ++n8)
#pragma unroll
            for (int ks = 0; ks < 2; ++ks) {
                short8 vf = *(const short8*)&Vc[(n8 * 2 + ks) * 512 + fr * 32 + g * 8];
                Oacc[n8] = __builtin_amdgcn_mfma_f32_16x16x32_bf16(pa[ks], vf, Oacc[n8], 0, 0, 0);
            }
        __builtin_amdgcn_s_setprio(0);
    }
    // ---- epilogue
#pragma unroll
    for (int j = 0; j < 4; ++j) {
        int qr = q0 + wave * 16 + g * 4 + j;
        float inv = 1.0f / lrow[j];
        ushort* orow = Ob + (size_t)(b * S_ + qr) * 2048 + h * 128;
#pragma unroll
        for (int n8 = 0; n8 < 8; ++n8) orow[n8 * 16 + fr] = f2b(Oacc[n8][j] * inv);
    }
}

// ---------------------------------------------------------------------------
extern "C" void kernel_launch(void* const* d_in, const int* in_sizes, int n_in,
                              void* d_out, int out_size, void* d_ws, size_t ws_size,
                              hipStream_t stream) {
    (void)in_sizes; (void)n_in; (void)out_size; (void)ws_size;
    const float* x = (const float*)d_in[0];
    const float* wq = (const float*)d_in[1];
    const float* w_kv_down = (const float*)d_in[2];
    const float* w_k_rope = (const float*)d_in[3];
    const float* w_k_nope = (const float*)d_in[4];
    const float* wv = (const float*)d_in[5];
    const float* wo = (const float*)d_in[6];
    const float* q_norm_w = (const float*)d_in[7];
    const float* k_norm_w = (const float*)d_in[8];
    float* out = (float*)d_out;

    char* ws = (char*)d_ws;
    size_t off = 0;
    auto alloc = [&](size_t bytes) {
        off = (off + 255) & ~(size_t)255;
        void* p = ws + off;
        off += bytes;
        return p;
    };
    ushort* xb = (ushort*)alloc((size_t)BS_ * 2048 * 2);
    ushort* wq_t = (ushort*)alloc((size_t)2048 * 2048 * 2);
    ushort* wkv_t = (ushort*)alloc((size_t)512 * 2048 * 2);
    ushort* wkrnv_t = (ushort*)alloc((size_t)4096 * 512 * 2);   // [kr 1024][kn 1024][v 2048] x 512
    ushort* wo_t = (ushort*)alloc((size_t)2048 * 2048 * 2);
    ushort* q_pre_b = (ushort*)alloc((size_t)BS_ * 2048 * 2);
    ushort* latent_b = (ushort*)alloc((size_t)BS_ * 512 * 2);
    ushort* krnv_b = (ushort*)alloc((size_t)BS_ * 4096 * 2);
    ushort* q_b = (ushort*)alloc((size_t)BS_ * 2048 * 2);
    ushort* k_b = (ushort*)alloc((size_t)BS_ * 2048 * 2);
    ushort* vt = (ushort*)alloc((size_t)BS_ * 2048 * 2);
    ushort* ao_b = (ushort*)alloc((size_t)BS_ * 2048 * 2);
    float* cosT = (float*)alloc((size_t)S_ * 32 * 4);
    float* sinT = (float*)alloc((size_t)S_ * 32 * 4);

    // 1) all prep in one dispatch
    prep<<<19712, 256, 0, stream>>>(x, xb, wq, wq_t, w_kv_down, wkv_t,
                                    w_k_rope, w_k_nope, wv, wkrnv_t, wo, wo_t,
                                    cosT, sinT);
    // 2) q-proj + latent-proj fused
    gemm_qlat<<<dim3(20, 32), 256, 0, stream>>>(xb, wq_t, wkv_t, q_pre_b, latent_b);
    // 3) fused kr/kn/v projection
    gemm_bt<1><<<dim3(32, 32), 256, 0, stream>>>(latent_b, wkrnv_t, krnv_b, 4096, 512);
    // 4) norms + rope + v transpose
    epi<<<40960, 256, 0, stream>>>(q_pre_b, krnv_b, q_norm_w, k_norm_w,
                                   cosT, sinT, q_b, k_b, vt);
    // 5) attention: 512 blocks, 2/CU
    attn_fwd<<<dim3(32, 16), 512, 0, stream>>>(q_b, k_b, vt, ao_b);
    // 6) output projection
    gemm_bt<0><<<dim3(16, 32), 256, 0, stream>>>(ao_b, wo_t, out, 2048, 2048);
}